// Round 2
// baseline (181.705 us; speedup 1.0000x reference)
//
#include <hip/hip_runtime.h>
#include <math.h>

// Problem constants (match the reference)
constexpr int B    = 4;
constexpr int N    = 65536;   // 2^16
constexpr int NSUB = 16384;   // 2^14
constexpr int K    = 16;
constexpr int D    = 32;      // 8 float4 per row
constexpr int D4   = D / 4;   // 8

__device__ inline float4 fmax4(float4 a, float4 b) {
    return make_float4(fmaxf(a.x, b.x), fmaxf(a.y, b.y),
                       fmaxf(a.z, b.z), fmaxf(a.w, b.w));
}

// dst[b, r, :] = max_k src[b, idx[b, r, k], :]
// src has NSRC rows per batch (8 MiB for NSRC=65536 — exceeds the 4 MiB
// per-XCD L2). Two-pass range split: pass A gathers only idx < NSRC/2,
// pass B the rest, so the device-wide hot set per pass is ~4 MiB/batch and
// stays L2-resident. __syncthreads() between passes is a soft phase
// barrier (blocks dispatch roughly in order, so the whole device moves
// through the table halves together).
// 8 threads per row, one float4 each (coalesced 128 B per gathered row).
template<int M, int NSRC>
__global__ __launch_bounds__(256)
void gather_max_split_k(const float* __restrict__ src,
                        const int*   __restrict__ idx,
                        float*       __restrict__ dst)
{
    const int t = blockIdx.x * 256 + threadIdx.x;   // B*M*8 threads total
    const int r = t >> 3;                           // global row in [0, B*M)
    const int j = t & 7;                            // float4 slot within row
    const int b = r / M;                            // compile-time pow2 -> shift

    // Preload all 16 indices (4x int4, 64B-aligned since K=16).
    const int4* ip4 = (const int4*)(idx + (size_t)r * K);
    int inds[K];
#pragma unroll
    for (int q = 0; q < K / 4; ++q) {
        int4 v = ip4[q];
        inds[4 * q + 0] = v.x; inds[4 * q + 1] = v.y;
        inds[4 * q + 2] = v.z; inds[4 * q + 3] = v.w;
    }

    const float4* sb = (const float4*)src + (size_t)b * NSRC * D4;

    float4 m = make_float4(-INFINITY, -INFINITY, -INFINITY, -INFINITY);

    // Pass A: lower half of the table (hot set ~4 MiB/batch, L2-resident)
#pragma unroll
    for (int k = 0; k < K; ++k) {
        if (inds[k] < NSRC / 2) {
            m = fmax4(m, sb[(size_t)inds[k] * D4 + j]);
        }
    }

    __syncthreads();   // phase hint: keep the device in the same half

    // Pass B: upper half
#pragma unroll
    for (int k = 0; k < K; ++k) {
        if (inds[k] >= NSRC / 2) {
            m = fmax4(m, sb[(size_t)inds[k] * D4 + j]);
        }
    }

    ((float4*)dst)[(size_t)r * D4 + j] = m;
}

// out[b, n, :] += pooled[b, interp_idx[b, n], :]   (in-place on agg)
// pooled is only 2 MiB/batch -> L2-resident, no split needed.
__global__ __launch_bounds__(256)
void interp_add_k(const float* __restrict__ pooled,
                  const int*   __restrict__ iidx,
                  float*       __restrict__ out)
{
    const int t = blockIdx.x * 256 + threadIdx.x;   // B*N*8 threads
    const int r = t >> 3;                           // global row in [0, B*N)
    const int j = t & 7;
    const int b = r >> 16;                          // r / N

    const int s = iidx[r];
    float4 p = ((const float4*)pooled)[((size_t)b * NSUB + s) * D4 + j];

    float4* op = (float4*)out + (size_t)r * D4 + j;
    float4 o = *op;
    *op = make_float4(o.x + p.x, o.y + p.y, o.z + p.z, o.w + p.w);
}

extern "C" void kernel_launch(void* const* d_in, const int* in_sizes, int n_in,
                              void* d_out, int out_size, void* d_ws, size_t ws_size,
                              hipStream_t stream)
{
    const float* feature      = (const float*)d_in[0]; // [B, N, 1, D]
    const int*   neighbor_idx = (const int*)  d_in[1]; // [B, N, K]
    const int*   pool_idx     = (const int*)  d_in[2]; // [B, NSUB, K]
    const int*   interp_idx   = (const int*)  d_in[3]; // [B, N, 1]

    float* out    = (float*)d_out;   // agg lives here, then out = agg + up in-place
    float* pooled = (float*)d_ws;    // B*NSUB*D floats = 8 MiB scratch

    // 1) agg[b,n,:] = max_k feature[b, nidx, :]  -> d_out
    {
        const int threads = B * N * 8;
        gather_max_split_k<N, N><<<threads / 256, 256, 0, stream>>>(
            feature, neighbor_idx, out);
    }
    // 2) pooled[b,m,:] = max_k agg[b, pidx, :]   -> d_ws
    {
        const int threads = B * NSUB * 8;
        gather_max_split_k<NSUB, N><<<threads / 256, 256, 0, stream>>>(
            out, pool_idx, pooled);
    }
    // 3) out[b,n,:] = agg[b,n,:] + pooled[b, interp_idx[b,n], :]
    {
        const int threads = B * N * 8;
        interp_add_k<<<threads / 256, 256, 0, stream>>>(pooled, interp_idx, out);
    }
}

// Round 3
// 176.601 us; speedup vs baseline: 1.0289x; 1.0289x over previous
//
#include <hip/hip_runtime.h>
#include <math.h>

// Problem constants (match the reference)
constexpr int B    = 4;
constexpr int N    = 65536;   // 2^16
constexpr int NSUB = 16384;   // 2^14
constexpr int K    = 16;
constexpr int D    = 32;      // 8 float4 per row
constexpr int D4   = D / 4;   // 8

__device__ inline float4 fmax4(float4 a, float4 b) {
    return make_float4(fmaxf(a.x, b.x), fmaxf(a.y, b.y),
                       fmaxf(a.z, b.z), fmaxf(a.w, b.w));
}

// dst[b, r, :] = max_k src[b, idx[b, r, k], :]
// Two-phase table split so the device-wide hot set per phase is ~4 MiB/batch
// (fits per-XCD L2). Gathers are UNCONDITIONAL (address clamped into the
// phase's half, value selected vs -INF branchlessly) so all K loads of a
// phase issue back-to-back — full MLP, no exec-mask branches (R2's mistake).
// Out-of-range lanes load the clamped boundary row, which stays L1-resident.
template<int M, int NSRC>
__global__ __launch_bounds__(256)
void gather_max_split_k(const float* __restrict__ src,
                        const int*   __restrict__ idx,
                        float*       __restrict__ dst)
{
    constexpr int HALF = NSRC / 2;

    const int t = blockIdx.x * 256 + threadIdx.x;   // B*M*8 threads total
    const int r = t >> 3;                           // global row in [0, B*M)
    const int j = t & 7;                            // float4 slot within row
    const int b = r / M;                            // compile-time pow2 -> shift

    const int*    ip = idx + (size_t)r * K;
    const float4* sb = (const float4*)src + (size_t)b * NSRC * D4;

    float4 m = make_float4(-INFINITY, -INFINITY, -INFINITY, -INFINITY);

    // Phase A: lower half of the table (hot set ~4 MiB/batch, L2-resident)
#pragma unroll
    for (int k = 0; k < K; ++k) {
        int v = ip[k];
        int ia = v < HALF ? v : (HALF - 1);         // clamp into lower half
        float4 x = sb[(size_t)ia * D4 + j];         // unconditional load
        bool in = (v < HALF);
        m.x = fmaxf(m.x, in ? x.x : -INFINITY);
        m.y = fmaxf(m.y, in ? x.y : -INFINITY);
        m.z = fmaxf(m.z, in ? x.z : -INFINITY);
        m.w = fmaxf(m.w, in ? x.w : -INFINITY);
    }

    __builtin_amdgcn_sched_barrier(0);  // don't let phase-B loads hoist up
    __syncthreads();                    // phase-align the block's waves

    // Phase B: upper half
#pragma unroll
    for (int k = 0; k < K; ++k) {
        int v = ip[k];
        int ib = v >= HALF ? v : HALF;              // clamp into upper half
        float4 x = sb[(size_t)ib * D4 + j];         // unconditional load
        bool in = (v >= HALF);
        m.x = fmaxf(m.x, in ? x.x : -INFINITY);
        m.y = fmaxf(m.y, in ? x.y : -INFINITY);
        m.z = fmaxf(m.z, in ? x.z : -INFINITY);
        m.w = fmaxf(m.w, in ? x.w : -INFINITY);
    }

    ((float4*)dst)[(size_t)r * D4 + j] = m;
}

// out[b, n, :] += pooled[b, interp_idx[b, n], :]   (in-place on agg)
// pooled is only 2 MiB/batch -> L2-resident, no split needed.
__global__ __launch_bounds__(256)
void interp_add_k(const float* __restrict__ pooled,
                  const int*   __restrict__ iidx,
                  float*       __restrict__ out)
{
    const int t = blockIdx.x * 256 + threadIdx.x;   // B*N*8 threads
    const int r = t >> 3;                           // global row in [0, B*N)
    const int j = t & 7;
    const int b = r >> 16;                          // r / N

    const int s = iidx[r];
    float4 p = ((const float4*)pooled)[((size_t)b * NSUB + s) * D4 + j];

    float4* op = (float4*)out + (size_t)r * D4 + j;
    float4 o = *op;
    *op = make_float4(o.x + p.x, o.y + p.y, o.z + p.z, o.w + p.w);
}

extern "C" void kernel_launch(void* const* d_in, const int* in_sizes, int n_in,
                              void* d_out, int out_size, void* d_ws, size_t ws_size,
                              hipStream_t stream)
{
    const float* feature      = (const float*)d_in[0]; // [B, N, 1, D]
    const int*   neighbor_idx = (const int*)  d_in[1]; // [B, N, K]
    const int*   pool_idx     = (const int*)  d_in[2]; // [B, NSUB, K]
    const int*   interp_idx   = (const int*)  d_in[3]; // [B, N, 1]

    float* out    = (float*)d_out;   // agg lives here, then out = agg + up in-place
    float* pooled = (float*)d_ws;    // B*NSUB*D floats = 8 MiB scratch

    // 1) agg[b,n,:] = max_k feature[b, nidx, :]  -> d_out
    {
        const int threads = B * N * 8;
        gather_max_split_k<N, N><<<threads / 256, 256, 0, stream>>>(
            feature, neighbor_idx, out);
    }
    // 2) pooled[b,m,:] = max_k agg[b, pidx, :]   -> d_ws
    {
        const int threads = B * NSUB * 8;
        gather_max_split_k<NSUB, N><<<threads / 256, 256, 0, stream>>>(
            out, pool_idx, pooled);
    }
    // 3) out[b,n,:] = agg[b,n,:] + pooled[b, interp_idx[b,n], :]
    {
        const int threads = B * N * 8;
        interp_add_k<<<threads / 256, 256, 0, stream>>>(pooled, interp_idx, out);
    }
}

// Round 4
// 163.110 us; speedup vs baseline: 1.1140x; 1.0827x over previous
//
#include <hip/hip_runtime.h>
#include <math.h>

// Problem constants (match the reference)
constexpr int B    = 4;
constexpr int N    = 65536;   // 2^16
constexpr int NSUB = 16384;   // 2^14
constexpr int K    = 16;
constexpr int D    = 32;      // 8 float4 per row
constexpr int D4   = D / 4;   // 8

__device__ inline float4 fmax4(float4 a, float4 b) {
    return make_float4(fmaxf(a.x, b.x), fmaxf(a.y, b.y),
                       fmaxf(a.z, b.z), fmaxf(a.w, b.w));
}

// XCD-pinned block decode: MI355X dispatches blocks round-robin over 8 XCDs
// (xcd = blockIdx % 8). Mapping batch = (blockIdx%8)>>1 pins each batch's
// gathers to one XCD pair, so each 4 MiB L2 serves only that batch's 8 MiB
// table (2x oversubscription instead of 8x). Pure scheduling — no inner-loop
// cost (R2/R3's phase-split attempts paid VALU/branch cost and couldn't hold
// device-wide phases anyway).
__device__ inline void xcd_decode(int blk, int& b, int& pos) {
    const int xcd = blk & 7;
    b   = xcd >> 1;                        // batch 0..3 -> XCD pair {2b,2b+1}
    pos = ((blk >> 3) << 1) | (xcd & 1);   // within-batch block index
}

// agg[b,n,:] = max_k feature[b, neighbor_idx[b,n,k], :]
// 8 threads per row, one float4 each (one 128B L2 line per gathered row).
__global__ __launch_bounds__(256)
void k1_neigh_max(const float* __restrict__ feature,
                  const int*   __restrict__ nidx,
                  float*       __restrict__ agg)
{
    int b, pos;
    xcd_decode(blockIdx.x, b, pos);                 // pos in [0, 2048)
    const int rloc = pos * 32 + (threadIdx.x >> 3); // row within batch [0, N)
    const int j    = threadIdx.x & 7;
    const int r    = b * N + rloc;                  // global row

    const int*    ip = nidx + (size_t)r * K;
    const float4* sb = (const float4*)feature + (size_t)b * N * D4;

    int n0 = ip[0];
    float4 m = sb[(size_t)n0 * D4 + j];
#pragma unroll
    for (int k = 1; k < K; ++k) {
        int nn = ip[k];
        m = fmax4(m, sb[(size_t)nn * D4 + j]);
    }
    ((float4*)agg)[(size_t)r * D4 + j] = m;
}

// pooled[b,m,:] = max_k agg[b, pool_idx[b,m,k], :]
// Same pinning: batch b's agg table was written by the same XCD pair in k1,
// so many lines are still L2-resident here.
__global__ __launch_bounds__(256)
void k2_pool_max(const float* __restrict__ agg,
                 const int*   __restrict__ pidx,
                 float*       __restrict__ pooled)
{
    int b, pos;
    xcd_decode(blockIdx.x, b, pos);                 // pos in [0, 512)
    const int rloc = pos * 32 + (threadIdx.x >> 3); // row within batch [0, NSUB)
    const int j    = threadIdx.x & 7;
    const int r    = b * NSUB + rloc;

    const int*    ip = pidx + (size_t)r * K;
    const float4* sb = (const float4*)agg + (size_t)b * N * D4;

    int n0 = ip[0];
    float4 m = sb[(size_t)n0 * D4 + j];
#pragma unroll
    for (int k = 1; k < K; ++k) {
        int nn = ip[k];
        m = fmax4(m, sb[(size_t)nn * D4 + j]);
    }
    ((float4*)pooled)[(size_t)r * D4 + j] = m;
}

// out[b,n,:] += pooled[b, interp_idx[b,n], :]   (in-place on agg)
// pooled is 2 MiB/batch -> L2-resident everywhere; streaming otherwise.
__global__ __launch_bounds__(256)
void k3_interp_add(const float* __restrict__ pooled,
                   const int*   __restrict__ iidx,
                   float*       __restrict__ out)
{
    const int t = blockIdx.x * 256 + threadIdx.x;   // B*N*8 threads
    const int r = t >> 3;                           // global row in [0, B*N)
    const int j = t & 7;
    const int b = r >> 16;                          // r / N

    const int s = iidx[r];
    float4 p = ((const float4*)pooled)[((size_t)b * NSUB + s) * D4 + j];

    float4* op = (float4*)out + (size_t)r * D4 + j;
    float4 o = *op;
    *op = make_float4(o.x + p.x, o.y + p.y, o.z + p.z, o.w + p.w);
}

extern "C" void kernel_launch(void* const* d_in, const int* in_sizes, int n_in,
                              void* d_out, int out_size, void* d_ws, size_t ws_size,
                              hipStream_t stream)
{
    const float* feature      = (const float*)d_in[0]; // [B, N, 1, D]
    const int*   neighbor_idx = (const int*)  d_in[1]; // [B, N, K]
    const int*   pool_idx     = (const int*)  d_in[2]; // [B, NSUB, K]
    const int*   interp_idx   = (const int*)  d_in[3]; // [B, N, 1]

    float* out    = (float*)d_out;   // agg lives here, then out = agg + up in-place
    float* pooled = (float*)d_ws;    // B*NSUB*D floats = 8 MiB scratch

    // 1) agg -> d_out.  B*N*8 threads, 8192 blocks (2048 per batch).
    k1_neigh_max<<<B * N * 8 / 256, 256, 0, stream>>>(feature, neighbor_idx, out);
    // 2) pooled -> d_ws.  B*NSUB*8 threads, 2048 blocks (512 per batch).
    k2_pool_max<<<B * NSUB * 8 / 256, 256, 0, stream>>>(out, pool_idx, pooled);
    // 3) out = agg + pooled[interp]
    k3_interp_add<<<B * N * 8 / 256, 256, 0, stream>>>(pooled, interp_idx, out);
}